// Round 9
// baseline (39.840 us; speedup 1.0000x reference)
//
#include <hip/hip_runtime.h>
#include <math.h>
#include <float.h>
#include <limits.h>

#define CS   128            // points per chunk
#define SUBS 32             // points per sub-chunk (selection granularity)
#define CT   16             // chunks per K1 block
#define TILE_PTS (CT * CS)  // 2048 staged points per K1 block
#define CSP  129            // padded chunk stride in float4 (bank-balanced)
#define QB1  64             // queries per K1 block
#define QT   16             // queries per wave in K1
#define LCAP 12             // compacted sub-chunk list capacity
#define MARGIN 0.05f
typedef unsigned long long ull;
#define KMAX 0xFFFFFFFFFFFFFFFFull

// monotone float -> ordered u32 (handles negatives)
__device__ __forceinline__ unsigned int ford(float f) {
    unsigned int b = __float_as_uint(f);
    return b ^ (((unsigned int)((int)b >> 31)) | 0x80000000u);
}
__device__ __forceinline__ float funord(unsigned int u) {
    unsigned int m = ((u >> 31) - 1u) | 0x80000000u;
    return __uint_as_float(u ^ m);
}

__device__ __forceinline__ ull umin64(ull a, ull b) { return a < b ? a : b; }
__device__ __forceinline__ ull umax64(ull a, ull b) { return a > b ? a : b; }

// branchless sorted-3 insert on u64 keys (k0<=k1<=k2)
__device__ __forceinline__ void ins3k(ull k, ull& k0, ull& k1, ull& k2) {
    ull n2 = umax64(k1, umin64(k2, k));   // med3(k1,k2,k)
    ull n1 = umax64(k0, umin64(k1, k));   // med3(k0,k1,k)
    k0 = umin64(k0, k);
    k1 = n1;
    k2 = n2;
}

// branchless sorted-3 insert, f32 values only
__device__ __forceinline__ void sins(float d, float& a0, float& a1, float& a2)
{
    float n1 = __builtin_amdgcn_fmed3f(a0, a1, d);
    float n2 = __builtin_amdgcn_fmed3f(a1, a2, d);
    a0 = fminf(a0, d);
    a1 = n1;
    a2 = n2;
}

// pose_0to1 = inv(pose1) @ pose0 (SE3 analytic)
__device__ __forceinline__ void pose_rel(const float* __restrict__ P0,
                                         const float* __restrict__ P1,
                                         float R[3][3], float tv[3])
{
    float dt0 = P0[3]  - P1[3];
    float dt1 = P0[7]  - P1[7];
    float dt2 = P0[11] - P1[11];
    #pragma unroll
    for (int i = 0; i < 3; ++i) {
        float a0 = P1[i], a1 = P1[4 + i], a2 = P1[8 + i];   // col i of R1
        #pragma unroll
        for (int j = 0; j < 3; ++j)
            R[i][j] = fmaf(a2, P0[8 + j], fmaf(a1, P0[4 + j], a0 * P0[j]));
        tv[i] = fmaf(a2, dt2, fmaf(a1, dt1, a0 * dt0));
    }
}

// ---------------- K1: per-(query, 32-pt sub-chunk) key-min table ----------------
// key(q,m) = r2 - 2*cross  (q2 dropped: constant per query, order-preserving)
// Also exports ptile[b][m] = (-2x,-2y,-2z,r2) once (blockIdx.x==0 slice).
__launch_bounds__(256, 4)
__global__ void knn_phaseA(const float* __restrict__ pc0,
                           const float* __restrict__ pc1,
                           const float* __restrict__ pose0,
                           const float* __restrict__ pose1,
                           float* __restrict__ submin,
                           float4* __restrict__ ptile,
                           int B, int N, int M, int nsub)
{
    __shared__ float4 tile[CT * CSP];   // (-2x,-2y,-2z,r2), chunk-major padded
    __shared__ float4 qd[QB1];          // (qx,qy,qz,q2)

    const int tid = threadIdx.x;
    const int b   = blockIdx.z;
    const int ctb = blockIdx.y;               // chunk-tile index
    const int qb  = blockIdx.x * QB1;         // first query of block
    const int pbase = ctb * TILE_PTS;         // first staged point

    // ---- stage 64 transformed queries into LDS ----
    if (tid < QB1) {
        float R[3][3], tv[3];
        pose_rel(pose0 + b * 16, pose1 + b * 16, R, tv);
        int qg0 = qb + tid;
        int qg  = (qg0 < N) ? qg0 : (N - 1);
        const float px = pc0[(size_t)(b * N + qg) * 3 + 0];
        const float py = pc0[(size_t)(b * N + qg) * 3 + 1];
        const float pz = pc0[(size_t)(b * N + qg) * 3 + 2];
        float qx = fmaf(R[0][2], pz, fmaf(R[0][1], py, R[0][0] * px)) + tv[0];
        float qy = fmaf(R[1][2], pz, fmaf(R[1][1], py, R[1][0] * px)) + tv[1];
        float qz = fmaf(R[2][2], pz, fmaf(R[2][1], py, R[2][0] * px)) + tv[2];
        qd[tid] = make_float4(qx, qy, qz,
                              (qx * qx + qy * qy) + qz * qz);
    }

    // ---- stage 2048 points, 4 pts (3x dwordx4) per thread per round ----
    const bool wr = (blockIdx.x == 0);
    #pragma unroll
    for (int k = 0; k < TILE_PTS / (256 * 4); ++k) {
        const int pl = (tid + k * 256) * 4;
        const int p  = pbase + pl;
        float4* dst = &tile[(pl >> 7) * CSP + (pl & (CS - 1))];
        float4 w0, w1, w2, w3;
        if (p + 3 < M) {
            const float4* pf = (const float4*)(pc1 + (size_t)(b * M + p) * 3);
            float4 A = pf[0], Bv = pf[1], C = pf[2];
            w0 = make_float4(-2.f * A.x, -2.f * A.y, -2.f * A.z,
                             (A.x * A.x + A.y * A.y) + A.z * A.z);
            w1 = make_float4(-2.f * A.w, -2.f * Bv.x, -2.f * Bv.y,
                             (A.w * A.w + Bv.x * Bv.x) + Bv.y * Bv.y);
            w2 = make_float4(-2.f * Bv.z, -2.f * Bv.w, -2.f * C.x,
                             (Bv.z * Bv.z + Bv.w * Bv.w) + C.x * C.x);
            w3 = make_float4(-2.f * C.y, -2.f * C.z, -2.f * C.w,
                             (C.y * C.y + C.z * C.z) + C.w * C.w);
        } else {
            float4 tmp[4];
            #pragma unroll
            for (int u = 0; u < 4; ++u) {
                int pp = p + u;
                if (pp < M) {
                    const float* s = pc1 + (size_t)(b * M + pp) * 3;
                    float x = s[0], y = s[1], z = s[2];
                    tmp[u] = make_float4(-2.f * x, -2.f * y, -2.f * z,
                                         (x * x + y * y) + z * z);
                } else {
                    tmp[u] = make_float4(0.f, 0.f, 0.f, FLT_MAX);
                }
            }
            w0 = tmp[0]; w1 = tmp[1]; w2 = tmp[2]; w3 = tmp[3];
        }
        dst[0] = w0; dst[1] = w1; dst[2] = w2; dst[3] = w3;
        if (wr) {
            float4* gp = &ptile[(size_t)b * M + p];
            if (p + 3 < M) { gp[0] = w0; gp[1] = w1; gp[2] = w2; gp[3] = w3; }
            else {
                if (p + 0 < M) gp[0] = w0;
                if (p + 1 < M) gp[1] = w1;
                if (p + 2 < M) gp[2] = w2;
                if (p + 3 < M) gp[3] = w3;
            }
        }
    }
    __syncthreads();

    // ---- scan: wave w handles 16 queries; lane = (part, chunk) ----
    const int w    = tid >> 6;
    const int lane = tid & 63;
    const int cl   = lane & 15;       // local chunk
    const int part = lane >> 4;       // 32-pt quarter == sub-chunk

    float4 qv[QT];
    #pragma unroll
    for (int t = 0; t < QT; ++t) qv[t] = qd[w * QT + t];

    float mm[QT];
    #pragma unroll
    for (int t = 0; t < QT; ++t) mm[t] = FLT_MAX;

    const float4* tp = &tile[cl * CSP + part * 32];
    #pragma unroll 4
    for (int i = 0; i < 32; ++i) {
        const float4 v = tp[i];
        #pragma unroll
        for (int t = 0; t < QT; ++t)
            mm[t] = fminf(mm[t],
                fmaf(qv[t].x, v.x, fmaf(qv[t].y, v.y, fmaf(qv[t].z, v.z, v.w))));
    }

    // ---- write per-lane 32-pt sub-chunk mins directly (no shfl merge) ----
    const int sg = (ctb * CT + cl) * 4 + part;    // global sub-chunk id
    #pragma unroll
    for (int t = 0; t < QT; ++t) {
        int qg0 = qb + w * QT + t;
        int qg  = (qg0 < N) ? qg0 : (N - 1);
        submin[((size_t)b * N + qg) * nsub + sg] = mm[t];
    }
}

// ---------------- K2: threshold + compaction + exact rescan + outputs ----------------
// 4 queries per wave, 16 lanes each (all reductions 4 levels, masks 1..8)
__launch_bounds__(256, 8)
__global__ void knn_select(const float* __restrict__ pc0,
                           const float* __restrict__ flow1,
                           const float* __restrict__ pose0,
                           const float* __restrict__ pose1,
                           const float* __restrict__ submin,
                           const float4* __restrict__ ptile,
                           float* __restrict__ out,
                           int B, int N, int M, int nsub)
{
    __shared__ unsigned char list[16][LCAP];   // rows 12B (4B-aligned)
    __shared__ int cnt[16];

    const int tid  = threadIdx.x;
    const int w    = tid >> 6;
    const int lane = tid & 63;
    const int g    = lane >> 4;        // query group in wave
    const int l    = lane & 15;        // lane within group
    const int qi   = w * 4 + g;        // query in block 0..15
    const int b    = blockIdx.y;
    const int q0   = blockIdx.x * 16 + qi;
    const bool qvalid = (q0 < N);
    const int q    = qvalid ? q0 : (N - 1);

    // ---- load this lane's 16 submins (4x dwordx4) ----
    const size_t row = (size_t)(b * N + q) * nsub;
    const int sbase = l * 16;
    float4 sA, sB, sC, sD;
    {
        const float4 FM = make_float4(FLT_MAX, FLT_MAX, FLT_MAX, FLT_MAX);
        sA = (sbase +  3 < nsub) ? *(const float4*)&submin[row + sbase +  0] : FM;
        sB = (sbase +  7 < nsub) ? *(const float4*)&submin[row + sbase +  4] : FM;
        sC = (sbase + 11 < nsub) ? *(const float4*)&submin[row + sbase +  8] : FM;
        sD = (sbase + 15 < nsub) ? *(const float4*)&submin[row + sbase + 12] : FM;
    }

    // ---- query transform (redundant per lane) ----
    float R[3][3], tv[3];
    pose_rel(pose0 + b * 16, pose1 + b * 16, R, tv);
    const float px = pc0[(size_t)(b * N + q) * 3 + 0];
    const float py = pc0[(size_t)(b * N + q) * 3 + 1];
    const float pz = pc0[(size_t)(b * N + q) * 3 + 2];
    const float qx = fmaf(R[0][2], pz, fmaf(R[0][1], py, R[0][0] * px)) + tv[0];
    const float qy = fmaf(R[1][2], pz, fmaf(R[1][1], py, R[1][0] * px)) + tv[1];
    const float qz = fmaf(R[2][2], pz, fmaf(R[2][1], py, R[2][0] * px)) + tv[2];
    const float q2 = (qx * qx + qy * qy) + qz * qz;

    // ---- threshold: 3rd-smallest 128-pt chunk-min (chunkmin = min of 4 submins)
    float c0 = fminf(fminf(sA.x, sA.y), fminf(sA.z, sA.w));
    float c1 = fminf(fminf(sB.x, sB.y), fminf(sB.z, sB.w));
    float c2 = fminf(fminf(sC.x, sC.y), fminf(sC.z, sC.w));
    float c3 = fminf(fminf(sD.x, sD.y), fminf(sD.z, sD.w));
    float a0 = FLT_MAX, a1 = FLT_MAX, a2 = FLT_MAX;
    sins(c0, a0, a1, a2);
    sins(c1, a0, a1, a2);
    sins(c2, a0, a1, a2);
    sins(c3, a0, a1, a2);
    #pragma unroll
    for (int msk = 1; msk <= 8; msk <<= 1) {
        float o0 = __shfl_xor(a0, msk);
        float o1 = __shfl_xor(a1, msk);
        float o2 = __shfl_xor(a2, msk);
        sins(o0, a0, a1, a2);
        sins(o1, a0, a1, a2);
        sins(o2, a0, a1, a2);
    }
    const float thr = a2 + MARGIN;

    // ---- compact selected sub-chunks (wave-synchronous, per-group list) ----
    if (l == 0) cnt[qi] = 0;
    {
        float sv[16] = {sA.x, sA.y, sA.z, sA.w, sB.x, sB.y, sB.z, sB.w,
                        sC.x, sC.y, sC.z, sC.w, sD.x, sD.y, sD.z, sD.w};
        #pragma unroll
        for (int j = 0; j < 16; ++j) {
            if (sv[j] <= thr) {
                int s = atomicAdd(&cnt[qi], 1);
                if (s < LCAP) list[qi][s] = (unsigned char)(sbase + j);
            }
        }
    }
    const int c = cnt[qi];

    // prefetch list as 3 dwords (no LDS reads in rescan loop)
    unsigned int L0 = *(const unsigned int*)&list[qi][0];
    unsigned int L1 = *(const unsigned int*)&list[qi][4];
    unsigned int L2 = *(const unsigned int*)&list[qi][8];

    // ---- exact rescan; (d2,idx) packed u64, even/odd accumulator pairs ----
    ull kA0 = KMAX, kA1 = KMAX, kA2 = KMAX;
    ull kB0 = KMAX, kB1 = KMAX, kB2 = KMAX;
    const float4* pt = &ptile[(size_t)b * M];
    if (c <= LCAP) {
        #pragma unroll
        for (int i = 0; i < LCAP; ++i) {
            if (i < c) {
                unsigned int word = (i < 4) ? L0 : (i < 8) ? L1 : L2;
                int sub = (word >> (8 * (i & 3))) & 0xFF;
                #pragma unroll
                for (int r = 0; r < SUBS / 16; ++r) {
                    const int m = sub * SUBS + r * 16 + l;
                    if (m < M) {
                        const float4 v = pt[m];
                        float t  = fmaf(qz, v.z, fmaf(qy, v.y, qx * v.x));
                        float dd = (q2 + v.w) + t;   // == fmaf(-2,cross,q2+r2)
                        ull kk = ((ull)ford(dd) << 32) | (unsigned int)m;
                        if (r & 1) ins3k(kk, kB0, kB1, kB2);
                        else       ins3k(kk, kA0, kA1, kA2);
                    }
                }
            }
        }
    } else {
        // overflow fallback (never expected): dense full scan
        int par = 0;
        for (int m = l; m < M; m += 16, par ^= 1) {
            const float4 v = pt[m];
            float t  = fmaf(qz, v.z, fmaf(qy, v.y, qx * v.x));
            float dd = (q2 + v.w) + t;
            ull kk = ((ull)ford(dd) << 32) | (unsigned int)m;
            if (par) ins3k(kk, kB0, kB1, kB2);
            else     ins3k(kk, kA0, kA1, kA2);
        }
    }
    ins3k(kB0, kA0, kA1, kA2);
    ins3k(kB1, kA0, kA1, kA2);
    ins3k(kB2, kA0, kA1, kA2);

    // ---- merge 16 lanes: 4-level butterfly of sorted triples ----
    #pragma unroll
    for (int msk = 1; msk <= 8; msk <<= 1) {
        ull o0 = __shfl_xor(kA0, msk);
        ull o1 = __shfl_xor(kA1, msk);
        ull o2 = __shfl_xor(kA2, msk);
        ins3k(o0, kA0, kA1, kA2);
        ins3k(o1, kA0, kA1, kA2);
        ins3k(o2, kA0, kA1, kA2);
    }

    if (l == 0 && qvalid) {
        // pose_flow
        size_t pf = (size_t)B * N * 3 + (size_t)(b * N + q) * 3;
        out[pf + 0] = qx - px;
        out[pf + 1] = qy - py;
        out[pf + 2] = qz - pz;

        float D0 = funord((unsigned int)(kA0 >> 32));
        float D1 = funord((unsigned int)(kA1 >> 32));
        float D2 = funord((unsigned int)(kA2 >> 32));
        int   i0 = (int)(unsigned int)kA0;
        int   i1 = (int)(unsigned int)kA1;
        int   i2 = (int)(unsigned int)kA2;

        float dd0 = sqrtf(fmaxf(D0, 0.f));
        float dd1 = sqrtf(fmaxf(D1, 0.f));
        float dd2 = sqrtf(fmaxf(D2, 0.f));
        float w0 = 1.0f / (dd0 + 1e-8f);
        float w1 = 1.0f / (dd1 + 1e-8f);
        float w2 = 1.0f / (dd2 + 1e-8f);
        float wsum = (w0 + w1) + w2;
        w0 /= wsum; w1 /= wsum; w2 /= wsum;

        const float* f0 = flow1 + (size_t)(b * M + i0) * 3;
        const float* f1 = flow1 + (size_t)(b * M + i1) * 3;
        const float* f2 = flow1 + (size_t)(b * M + i2) * 3;

        const size_t ob = (size_t)(b * N + q) * 3;
        #pragma unroll
        for (int ch = 0; ch < 3; ++ch) {
            float p0 = w0 * f0[ch];
            float p1 = w1 * f1[ch];
            float p2 = w2 * f2[ch];
            out[ob + ch] = (p0 + p1) + p2;
        }
    }
}

extern "C" void kernel_launch(void* const* d_in, const int* in_sizes, int n_in,
                              void* d_out, int out_size, void* d_ws, size_t ws_size,
                              hipStream_t stream) {
    const float* pc0   = (const float*)d_in[0];
    const float* pc1   = (const float*)d_in[1];
    const float* flow1 = (const float*)d_in[2];
    const float* pose0 = (const float*)d_in[3];
    const float* pose1 = (const float*)d_in[4];
    float* out = (float*)d_out;

    const int B = in_sizes[3] / 16;
    const int N = in_sizes[0] / (3 * B);
    const int M = in_sizes[1] / (3 * B);

    const int nct  = (M + TILE_PTS - 1) / TILE_PTS;   // chunk-tiles
    const int nsub = nct * CT * 4;                    // 32-pt sub-chunks (256)

    float*  submin = (float*)d_ws;                    // B*N*nsub floats (~16.8 MB)
    float4* ptile  = (float4*)((char*)d_ws + (size_t)B * N * nsub * sizeof(float));

    dim3 g1((N + QB1 - 1) / QB1, nct, B);
    knn_phaseA<<<g1, dim3(256), 0, stream>>>(pc0, pc1, pose0, pose1,
                                             submin, ptile, B, N, M, nsub);

    dim3 g2((N + 15) / 16, B);
    knn_select<<<g2, dim3(256), 0, stream>>>(pc0, flow1, pose0, pose1,
                                             submin, ptile, out, B, N, M, nsub);
}

// Round 10
// 34.587 us; speedup vs baseline: 1.1519x; 1.1519x over previous
//
#include <hip/hip_runtime.h>
#include <math.h>
#include <float.h>
#include <limits.h>

#define CS   64             // points per chunk (selection granularity)
#define CT   32             // chunks per K1 block
#define TILE_PTS (CT * CS)  // 2048 staged points per K1 block
#define CSP  65             // padded chunk stride in float4
#define QB1  64             // queries per K1 block
#define QT   16             // queries per wave in K1
#define MARGIN 0.05f
typedef unsigned long long ull;
#define KMAX 0xFFFFFFFFFFFFFFFFull

// monotone float -> ordered u32 (handles negatives)
__device__ __forceinline__ unsigned int ford(float f) {
    unsigned int b = __float_as_uint(f);
    return b ^ (((unsigned int)((int)b >> 31)) | 0x80000000u);
}
__device__ __forceinline__ float funord(unsigned int u) {
    unsigned int m = ((u >> 31) - 1u) | 0x80000000u;
    return __uint_as_float(u ^ m);
}

__device__ __forceinline__ ull umin64(ull a, ull b) { return a < b ? a : b; }
__device__ __forceinline__ ull umax64(ull a, ull b) { return a > b ? a : b; }

// branchless sorted-3 insert on u64 keys (k0<=k1<=k2)
__device__ __forceinline__ void ins3k(ull k, ull& k0, ull& k1, ull& k2) {
    ull n2 = umax64(k1, umin64(k2, k));   // med3(k1,k2,k)
    ull n1 = umax64(k0, umin64(k1, k));   // med3(k0,k1,k)
    k0 = umin64(k0, k);
    k1 = n1;
    k2 = n2;
}

// branchless sorted-3 insert, f32 values only
__device__ __forceinline__ void sins(float d, float& a0, float& a1, float& a2)
{
    float n1 = __builtin_amdgcn_fmed3f(a0, a1, d);
    float n2 = __builtin_amdgcn_fmed3f(a1, a2, d);
    a0 = fminf(a0, d);
    a1 = n1;
    a2 = n2;
}

// pose_0to1 = inv(pose1) @ pose0 (SE3 analytic)
__device__ __forceinline__ void pose_rel(const float* __restrict__ P0,
                                         const float* __restrict__ P1,
                                         float R[3][3], float tv[3])
{
    float dt0 = P0[3]  - P1[3];
    float dt1 = P0[7]  - P1[7];
    float dt2 = P0[11] - P1[11];
    #pragma unroll
    for (int i = 0; i < 3; ++i) {
        float a0 = P1[i], a1 = P1[4 + i], a2 = P1[8 + i];   // col i of R1
        #pragma unroll
        for (int j = 0; j < 3; ++j)
            R[i][j] = fmaf(a2, P0[8 + j], fmaf(a1, P0[4 + j], a0 * P0[j]));
        tv[i] = fmaf(a2, dt2, fmaf(a1, dt1, a0 * dt0));
    }
}

// ---------------- K1: per-(query, 64-pt chunk) key-min table ----------------
// key(q,m) = r2 - 2*cross  (q2 dropped: constant per query, order-preserving)
__launch_bounds__(256, 4)
__global__ void knn_phaseA(const float* __restrict__ pc0,
                           const float* __restrict__ pc1,
                           const float* __restrict__ pose0,
                           const float* __restrict__ pose1,
                           float* __restrict__ cmin,
                           int B, int N, int M, int cstride)
{
    __shared__ float4 tile[CT * CSP];   // (-2x,-2y,-2z,r2), chunk-major padded
    __shared__ float4 qd[QB1];          // (qx,qy,qz,q2)

    const int tid = threadIdx.x;
    const int b   = blockIdx.z;
    const int ctb = blockIdx.y;               // chunk-tile index
    const int qb  = blockIdx.x * QB1;         // first query of block
    const int pbase = ctb * TILE_PTS;         // first staged point

    // ---- stage 64 transformed queries into LDS ----
    if (tid < QB1) {
        float R[3][3], tv[3];
        pose_rel(pose0 + b * 16, pose1 + b * 16, R, tv);
        int qg0 = qb + tid;
        int qg  = (qg0 < N) ? qg0 : (N - 1);
        const float px = pc0[(size_t)(b * N + qg) * 3 + 0];
        const float py = pc0[(size_t)(b * N + qg) * 3 + 1];
        const float pz = pc0[(size_t)(b * N + qg) * 3 + 2];
        float qx = fmaf(R[0][2], pz, fmaf(R[0][1], py, R[0][0] * px)) + tv[0];
        float qy = fmaf(R[1][2], pz, fmaf(R[1][1], py, R[1][0] * px)) + tv[1];
        float qz = fmaf(R[2][2], pz, fmaf(R[2][1], py, R[2][0] * px)) + tv[2];
        qd[tid] = make_float4(qx, qy, qz,
                              (qx * qx + qy * qy) + qz * qz);
    }

    // ---- stage 2048 points, 4 pts (3x dwordx4) per thread per round ----
    #pragma unroll
    for (int k = 0; k < TILE_PTS / (256 * 4); ++k) {
        const int pl = (tid + k * 256) * 4;
        const int p  = pbase + pl;
        float4* dst = &tile[(pl >> 6) * CSP + (pl & (CS - 1))];
        if (p + 3 < M) {
            const float4* pf = (const float4*)(pc1 + (size_t)(b * M + p) * 3);
            float4 A = pf[0], Bv = pf[1], C = pf[2];
            dst[0] = make_float4(-2.f * A.x, -2.f * A.y, -2.f * A.z,
                                 (A.x * A.x + A.y * A.y) + A.z * A.z);
            dst[1] = make_float4(-2.f * A.w, -2.f * Bv.x, -2.f * Bv.y,
                                 (A.w * A.w + Bv.x * Bv.x) + Bv.y * Bv.y);
            dst[2] = make_float4(-2.f * Bv.z, -2.f * Bv.w, -2.f * C.x,
                                 (Bv.z * Bv.z + Bv.w * Bv.w) + C.x * C.x);
            dst[3] = make_float4(-2.f * C.y, -2.f * C.z, -2.f * C.w,
                                 (C.y * C.y + C.z * C.z) + C.w * C.w);
        } else {
            #pragma unroll
            for (int u = 0; u < 4; ++u) {
                int pp = p + u;
                float4 v;
                if (pp < M) {
                    const float* s = pc1 + (size_t)(b * M + pp) * 3;
                    float x = s[0], y = s[1], z = s[2];
                    v = make_float4(-2.f * x, -2.f * y, -2.f * z,
                                    (x * x + y * y) + z * z);
                } else {
                    v = make_float4(0.f, 0.f, 0.f, FLT_MAX);
                }
                dst[u] = v;
            }
        }
    }
    __syncthreads();

    // ---- scan: wave w handles 16 queries; lane = (part, chunk) ----
    const int w    = tid >> 6;
    const int lane = tid & 63;
    const int cl   = lane & 31;       // local chunk 0..31
    const int part = lane >> 5;       // half of the chunk (32 pts)

    float4 qv[QT];
    #pragma unroll
    for (int t = 0; t < QT; ++t) qv[t] = qd[w * QT + t];

    float mm[QT];
    #pragma unroll
    for (int t = 0; t < QT; ++t) mm[t] = FLT_MAX;

    const float4* tp = &tile[cl * CSP + part * 32];
    #pragma unroll 4
    for (int i = 0; i < 32; ++i) {
        const float4 v = tp[i];
        #pragma unroll
        for (int t = 0; t < QT; ++t)
            mm[t] = fminf(mm[t],
                fmaf(qv[t].x, v.x, fmaf(qv[t].y, v.y, fmaf(qv[t].z, v.z, v.w))));
    }

    // merge the 2 parts of each chunk (lane bit 5)
    #pragma unroll
    for (int t = 0; t < QT; ++t)
        mm[t] = fminf(mm[t], __shfl_xor(mm[t], 32));

    if (part == 0) {
        const int cg = ctb * CT + cl;         // global chunk id
        #pragma unroll
        for (int t = 0; t < QT; ++t) {
            int qg0 = qb + w * QT + t;
            int qg  = (qg0 < N) ? qg0 : (N - 1);
            cmin[((size_t)b * N + qg) * cstride + cg] = mm[t];
        }
    }
}

// ---------------- K2: threshold + exact rescan + outputs ----------------
// 4 queries per wave, 16 lanes each (all reductions 4 levels, masks 1..8)
__launch_bounds__(256, 8)
__global__ void knn_select(const float* __restrict__ pc0,
                           const float* __restrict__ pc1,
                           const float* __restrict__ flow1,
                           const float* __restrict__ pose0,
                           const float* __restrict__ pose1,
                           const float* __restrict__ cmin,
                           float* __restrict__ out,
                           int B, int N, int M, int cstride)
{
    const int tid  = threadIdx.x;
    const int w    = tid >> 6;
    const int lane = tid & 63;
    const int g    = lane >> 4;        // query group in wave
    const int l    = lane & 15;        // lane within group
    const int b    = blockIdx.y;
    const int q0   = blockIdx.x * 16 + w * 4 + g;
    const bool qvalid = (q0 < N);
    const int q    = qvalid ? q0 : (N - 1);

    // ---- load this lane's 8 chunk-mins (2x dwordx4; table fully written) ----
    const size_t row = (size_t)(b * N + q) * cstride;
    const float4 sA = *(const float4*)&cmin[row + l * 8];
    const float4 sB = *(const float4*)&cmin[row + l * 8 + 4];

    // ---- query transform (redundant per lane) ----
    float R[3][3], tv[3];
    pose_rel(pose0 + b * 16, pose1 + b * 16, R, tv);
    const float px = pc0[(size_t)(b * N + q) * 3 + 0];
    const float py = pc0[(size_t)(b * N + q) * 3 + 1];
    const float pz = pc0[(size_t)(b * N + q) * 3 + 2];
    const float qx = fmaf(R[0][2], pz, fmaf(R[0][1], py, R[0][0] * px)) + tv[0];
    const float qy = fmaf(R[1][2], pz, fmaf(R[1][1], py, R[1][0] * px)) + tv[1];
    const float qz = fmaf(R[2][2], pz, fmaf(R[2][1], py, R[2][0] * px)) + tv[2];
    const float q2 = (qx * qx + qy * qy) + qz * qz;

    // ---- threshold: 3rd-smallest of 128 chunk-mins (8/lane + 4-level bfly) ----
    float a0 = FLT_MAX, a1 = FLT_MAX, a2 = FLT_MAX;
    sins(sA.x, a0, a1, a2); sins(sA.y, a0, a1, a2);
    sins(sA.z, a0, a1, a2); sins(sA.w, a0, a1, a2);
    sins(sB.x, a0, a1, a2); sins(sB.y, a0, a1, a2);
    sins(sB.z, a0, a1, a2); sins(sB.w, a0, a1, a2);
    #pragma unroll
    for (int msk = 1; msk <= 8; msk <<= 1) {
        float o0 = __shfl_xor(a0, msk);
        float o1 = __shfl_xor(a1, msk);
        float o2 = __shfl_xor(a2, msk);
        sins(o0, a0, a1, a2);
        sins(o1, a0, a1, a2);
        sins(o2, a0, a1, a2);
    }
    const float thr = a2 + MARGIN;

    // ---- two 64-bit chunk masks (chunks 0..63, 64..127), OR-butterfly ----
    unsigned int mbits =
          ((unsigned int)(sA.x <= thr) << 0) | ((unsigned int)(sA.y <= thr) << 1)
        | ((unsigned int)(sA.z <= thr) << 2) | ((unsigned int)(sA.w <= thr) << 3)
        | ((unsigned int)(sB.x <= thr) << 4) | ((unsigned int)(sB.y <= thr) << 5)
        | ((unsigned int)(sB.z <= thr) << 6) | ((unsigned int)(sB.w <= thr) << 7);
    ull m0 = (l < 8) ? ((ull)mbits << (8 * l)) : 0ull;
    ull m1 = (l >= 8) ? ((ull)mbits << (8 * (l - 8))) : 0ull;
    #pragma unroll
    for (int msk = 1; msk <= 8; msk <<= 1) {
        m0 |= __shfl_xor(m0, msk);
        m1 |= __shfl_xor(m1, msk);
    }

    // ---- dense rescan of selected 64-pt chunks (16 lanes, 4 rounds/chunk) ----
    // even/odd accumulator pair halves the serial ins3k chain
    ull kA0 = KMAX, kA1 = KMAX, kA2 = KMAX;
    ull kB0 = KMAX, kB1 = KMAX, kB2 = KMAX;
    #pragma unroll
    for (int half = 0; half < 2; ++half) {
        ull mask = half ? m1 : m0;
        const int cbase = half * 64;
        while (mask) {
            const int ck = (int)__builtin_ctzll(mask);
            mask &= mask - 1;
            const int mb = (cbase + ck) * CS;
            #pragma unroll
            for (int r = 0; r < CS / 16; ++r) {
                const int m = mb + r * 16 + l;
                if (m < M) {
                    const float* pp = pc1 + (size_t)(b * M + m) * 3;
                    float x = pp[0], y = pp[1], z = pp[2];
                    float r2 = (x * x + y * y) + z * z;
                    float cr = fmaf(qz, z, fmaf(qy, y, qx * x));
                    float dd = fmaf(-2.0f, cr, q2 + r2);     // exact ref rounding
                    ull kk = ((ull)ford(dd) << 32) | (unsigned int)m;
                    if (r & 1) ins3k(kk, kB0, kB1, kB2);
                    else       ins3k(kk, kA0, kA1, kA2);
                }
            }
        }
    }
    ins3k(kB0, kA0, kA1, kA2);
    ins3k(kB1, kA0, kA1, kA2);
    ins3k(kB2, kA0, kA1, kA2);

    // ---- merge 16 lanes: 4-level butterfly of sorted triples ----
    #pragma unroll
    for (int msk = 1; msk <= 8; msk <<= 1) {
        ull o0 = __shfl_xor(kA0, msk);
        ull o1 = __shfl_xor(kA1, msk);
        ull o2 = __shfl_xor(kA2, msk);
        ins3k(o0, kA0, kA1, kA2);
        ins3k(o1, kA0, kA1, kA2);
        ins3k(o2, kA0, kA1, kA2);
    }

    if (l == 0 && qvalid) {
        // pose_flow
        size_t pf = (size_t)B * N * 3 + (size_t)(b * N + q) * 3;
        out[pf + 0] = qx - px;
        out[pf + 1] = qy - py;
        out[pf + 2] = qz - pz;

        float D0 = funord((unsigned int)(kA0 >> 32));
        float D1 = funord((unsigned int)(kA1 >> 32));
        float D2 = funord((unsigned int)(kA2 >> 32));
        int   i0 = (int)(unsigned int)kA0;
        int   i1 = (int)(unsigned int)kA1;
        int   i2 = (int)(unsigned int)kA2;

        float dd0 = sqrtf(fmaxf(D0, 0.f));
        float dd1 = sqrtf(fmaxf(D1, 0.f));
        float dd2 = sqrtf(fmaxf(D2, 0.f));
        float w0 = 1.0f / (dd0 + 1e-8f);
        float w1 = 1.0f / (dd1 + 1e-8f);
        float w2 = 1.0f / (dd2 + 1e-8f);
        float wsum = (w0 + w1) + w2;
        w0 /= wsum; w1 /= wsum; w2 /= wsum;

        const float* f0 = flow1 + (size_t)(b * M + i0) * 3;
        const float* f1 = flow1 + (size_t)(b * M + i1) * 3;
        const float* f2 = flow1 + (size_t)(b * M + i2) * 3;

        const size_t ob = (size_t)(b * N + q) * 3;
        #pragma unroll
        for (int c = 0; c < 3; ++c) {
            float p0 = w0 * f0[c];
            float p1 = w1 * f1[c];
            float p2 = w2 * f2[c];
            out[ob + c] = (p0 + p1) + p2;
        }
    }
}

extern "C" void kernel_launch(void* const* d_in, const int* in_sizes, int n_in,
                              void* d_out, int out_size, void* d_ws, size_t ws_size,
                              hipStream_t stream) {
    const float* pc0   = (const float*)d_in[0];
    const float* pc1   = (const float*)d_in[1];
    const float* flow1 = (const float*)d_in[2];
    const float* pose0 = (const float*)d_in[3];
    const float* pose1 = (const float*)d_in[4];
    float* out = (float*)d_out;

    const int B = in_sizes[3] / 16;
    const int N = in_sizes[0] / (3 * B);
    const int M = in_sizes[1] / (3 * B);

    const int nct     = (M + TILE_PTS - 1) / TILE_PTS;   // chunk-tiles
    const int cstride = nct * CT;                        // chunk-min row stride (128)

    float* cmin = (float*)d_ws;   // B*N*cstride floats (~8.4 MB at 2x8192x128)

    dim3 g1((N + QB1 - 1) / QB1, nct, B);
    knn_phaseA<<<g1, dim3(256), 0, stream>>>(pc0, pc1, pose0, pose1,
                                             cmin, B, N, M, cstride);

    dim3 g2((N + 15) / 16, B);
    knn_select<<<g2, dim3(256), 0, stream>>>(pc0, pc1, flow1, pose0, pose1,
                                             cmin, out, B, N, M, cstride);
}